// Round 1
// baseline (2165.005 us; speedup 1.0000x reference)
//
#include <hip/hip_runtime.h>
#include <hip/hip_bf16.h>
#include <math.h>

#define NROWS 8192
#define DIM   1024
#define CAP   384
#define MARGIN 700.0f

using bf16x8 = __attribute__((ext_vector_type(8))) short;
using f32x4  = __attribute__((ext_vector_type(4))) float;

// ---------------- Kernel A: QKV projection, high-precision accumulate ----------
// C[row0+64][col0+64] = X[8192x1024] @ W[1024x1024], AccT accumulation.
template<typename AccT, bool WB16>
__global__ __launch_bounds__(256) void qkv_gemm(const float* __restrict__ X,
                                                const float* __restrict__ W,
                                                float* __restrict__ Out,
                                                __hip_bfloat16* __restrict__ Outb) {
    __shared__ float Xs[16][68];   // transposed X tile: Xs[k][row]
    __shared__ float Ws[16][68];   // Ws[k][col]
    const int tid = threadIdx.x;
    const int tx = tid & 15, ty = tid >> 4;
    const int row0 = blockIdx.x * 64;
    const int col0 = blockIdx.y * 64;

    AccT acc[4][4];
#pragma unroll
    for (int i = 0; i < 4; ++i)
#pragma unroll
        for (int j = 0; j < 4; ++j) acc[i][j] = (AccT)0;

    const int lr = tid >> 2;          // 0..63 : X row within tile
    const int lc = (tid & 3) * 4;     // 0,4,8,12 : k within tile
    const int wr = tid >> 4;          // 0..15 : W k-row
    const int wc = (tid & 15) * 4;    // col within tile

    for (int k0 = 0; k0 < DIM; k0 += 16) {
        float4 xa = *(const float4*)&X[(size_t)(row0 + lr) * DIM + k0 + lc];
        float4 wa = *(const float4*)&W[(size_t)(k0 + wr) * DIM + col0 + wc];
        __syncthreads();
        Xs[lc + 0][lr] = xa.x;
        Xs[lc + 1][lr] = xa.y;
        Xs[lc + 2][lr] = xa.z;
        Xs[lc + 3][lr] = xa.w;
        *(float4*)&Ws[wr][wc] = wa;
        __syncthreads();
#pragma unroll
        for (int k = 0; k < 16; ++k) {
            float4 a = *(const float4*)&Xs[k][ty * 4];
            float4 b = *(const float4*)&Ws[k][tx * 4];
            float av[4] = {a.x, a.y, a.z, a.w};
            float bv[4] = {b.x, b.y, b.z, b.w};
#pragma unroll
            for (int i = 0; i < 4; ++i)
#pragma unroll
                for (int j = 0; j < 4; ++j)
                    acc[i][j] += (AccT)av[i] * (AccT)bv[j];
        }
    }
#pragma unroll
    for (int i = 0; i < 4; ++i) {
        const int row = row0 + ty * 4 + i;
#pragma unroll
        for (int j = 0; j < 4; ++j) {
            const int col = col0 + tx * 4 + j;
            float v = (float)acc[i][j];
            Out[(size_t)row * DIM + col] = v;
            if (WB16) Outb[(size_t)row * DIM + col] = __float2bfloat16(v);
        }
    }
}

// ---------------- Kernel B: bf16 MFMA scores + candidate emission ---------------
// S = Qb @ Kb^T. Per (row, 32-col group): emit j where s >= groupmax - MARGIN.
__global__ __launch_bounds__(256) void score_kernel(const __hip_bfloat16* __restrict__ Qb,
                                                    const __hip_bfloat16* __restrict__ Kb,
                                                    int* __restrict__ cnt,
                                                    int2* __restrict__ cand) {
    const int tid  = threadIdx.x;
    const int w    = tid >> 6, lane = tid & 63;
    const int wy   = w >> 1,  wx   = w & 1;
    const int quad = lane >> 4, r16 = lane & 15;
    const int row0 = blockIdx.y * 64 + wy * 32;
    const int col0 = blockIdx.x * 64 + wx * 32;

    f32x4 acc[2][2] = {};
    const short* q  = (const short*)Qb;
    const short* kk = (const short*)Kb;
    const int dOff = quad * 8;

    for (int d = 0; d < DIM; d += 32) {
        // A frag: lane holds Q[row0(+16)+r16][d + quad*8 .. +8]
        bf16x8 a0 = *(const bf16x8*)&q[(size_t)(row0 + r16) * DIM + d + dOff];
        bf16x8 a1 = *(const bf16x8*)&q[(size_t)(row0 + 16 + r16) * DIM + d + dOff];
        // B frag (K^T): lane holds K[col0(+16)+r16][d + quad*8 .. +8]
        bf16x8 b0 = *(const bf16x8*)&kk[(size_t)(col0 + r16) * DIM + d + dOff];
        bf16x8 b1 = *(const bf16x8*)&kk[(size_t)(col0 + 16 + r16) * DIM + d + dOff];
        acc[0][0] = __builtin_amdgcn_mfma_f32_16x16x32_bf16(a0, b0, acc[0][0], 0, 0, 0);
        acc[0][1] = __builtin_amdgcn_mfma_f32_16x16x32_bf16(a0, b1, acc[0][1], 0, 0, 0);
        acc[1][0] = __builtin_amdgcn_mfma_f32_16x16x32_bf16(a1, b0, acc[1][0], 0, 0, 0);
        acc[1][1] = __builtin_amdgcn_mfma_f32_16x16x32_bf16(a1, b1, acc[1][1], 0, 0, 0);
    }

    // C/D layout: col = lane&15, row = quad*4 + reg  (m89-verified)
#pragma unroll
    for (int ty = 0; ty < 2; ++ty) {
#pragma unroll
        for (int reg = 0; reg < 4; ++reg) {
            float m = fmaxf(acc[ty][0][reg], acc[ty][1][reg]);
            m = fmaxf(m, __shfl_xor(m, 1, 64));
            m = fmaxf(m, __shfl_xor(m, 2, 64));
            m = fmaxf(m, __shfl_xor(m, 4, 64));
            m = fmaxf(m, __shfl_xor(m, 8, 64));
            const float th = m - MARGIN;
            const int row = row0 + ty * 16 + quad * 4 + reg;
#pragma unroll
            for (int tx = 0; tx < 2; ++tx) {
                float s = acc[ty][tx][reg];
                if (s >= th) {
                    int pos = atomicAdd(&cnt[row], 1);
                    if (pos < CAP)
                        cand[(size_t)row * CAP + pos] =
                            make_int2(col0 + tx * 16 + r16, __float_as_int(s));
                }
            }
        }
    }
}

// ---------------- Kernel E: exact sparse softmax + V gather --------------------
__global__ __launch_bounds__(256) void finalize_kernel(const float* __restrict__ Q,
                                                       const float* __restrict__ K,
                                                       const float* __restrict__ V,
                                                       const int* __restrict__ cnt,
                                                       const int2* __restrict__ cand,
                                                       float* __restrict__ out) {
    const int i = blockIdx.x;
    const int tid = threadIdx.x;
    __shared__ float  red[256];
    __shared__ double dred[256];
    __shared__ int    surv[64];
    __shared__ double sprec[64];
    __shared__ float  wgt[64];
    __shared__ int    nsurv;

    const int c = min(cnt[i], CAP);
    // phase 1: global max of approximate scores
    float m = -3.0e38f;
    for (int t = tid; t < c; t += 256)
        m = fmaxf(m, __int_as_float(cand[(size_t)i * CAP + t].y));
    red[tid] = m;
    __syncthreads();
    for (int s = 128; s > 0; s >>= 1) {
        if (tid < s) red[tid] = fmaxf(red[tid], red[tid + s]);
        __syncthreads();
    }
    const float th = red[0] - MARGIN;
    if (tid == 0) nsurv = 0;
    __syncthreads();
    // phase 2: survivors
    for (int t = tid; t < c; t += 256) {
        int2 e = cand[(size_t)i * CAP + t];
        if (__int_as_float(e.y) >= th) {
            int p = atomicAdd(&nsurv, 1);
            if (p < 64) surv[p] = e.x;
        }
    }
    __syncthreads();
    const int ns = min(nsurv, 64);
    // phase 3: fp64 precise rescore
    for (int u = 0; u < ns; ++u) {
        const int j = surv[u];
        double a = 0.0;
        for (int d = tid; d < DIM; d += 256)
            a += (double)Q[(size_t)i * DIM + d] * (double)K[(size_t)j * DIM + d];
        dred[tid] = a;
        __syncthreads();
        for (int s = 128; s > 0; s >>= 1) {
            if (tid < s) dred[tid] += dred[tid + s];
            __syncthreads();
        }
        if (tid == 0) sprec[u] = dred[0];
        __syncthreads();
    }
    // phase 4: exact softmax over survivors
    if (tid == 0) {
        double mm = -1.0e300;
        for (int u = 0; u < ns; ++u) mm = fmax(mm, sprec[u]);
        double l = 0.0;
        for (int u = 0; u < ns; ++u) l += exp(sprec[u] - mm);
        for (int u = 0; u < ns; ++u) wgt[u] = (float)(exp(sprec[u] - mm) / l);
    }
    __syncthreads();
    // phase 5: weighted gather of V rows
    for (int d = tid; d < DIM; d += 256) {
        float o = 0.f;
        for (int u = 0; u < ns; ++u) o += wgt[u] * V[(size_t)surv[u] * DIM + d];
        out[(size_t)i * DIM + d] = o;
    }
}

extern "C" void kernel_launch(void* const* d_in, const int* in_sizes, int n_in,
                              void* d_out, int out_size, void* d_ws, size_t ws_size,
                              hipStream_t stream) {
    const float* X  = (const float*)d_in[0];
    const float* wq = (const float*)d_in[1];
    const float* wk = (const float*)d_in[2];
    const float* wv = (const float*)d_in[3];
    float* out = (float*)d_out;

    char* ws = (char*)d_ws;
    const size_t mat_f32 = (size_t)NROWS * DIM * 4;   // 32 MB
    const size_t mat_b16 = (size_t)NROWS * DIM * 2;   // 16 MB
    float* Q            = (float*)(ws);
    float* K            = (float*)(ws + mat_f32);
    float* V            = (float*)(ws + 2 * mat_f32);
    __hip_bfloat16* Qb  = (__hip_bfloat16*)(ws + 3 * mat_f32);
    __hip_bfloat16* Kb  = (__hip_bfloat16*)(ws + 3 * mat_f32 + mat_b16);
    int* cnt            = (int*)(ws + 3 * mat_f32 + 2 * mat_b16);
    int2* cand          = (int2*)(ws + 3 * mat_f32 + 2 * mat_b16 + (size_t)NROWS * 4);

    hipMemsetAsync(cnt, 0, (size_t)NROWS * 4, stream);

    dim3 gA(NROWS / 64, DIM / 64);
    qkv_gemm<double, true ><<<gA, 256, 0, stream>>>(X, wq, Q, Qb);
    qkv_gemm<double, true ><<<gA, 256, 0, stream>>>(X, wk, K, Kb);
    qkv_gemm<float,  false><<<gA, 256, 0, stream>>>(X, wv, V, nullptr);

    dim3 gB(NROWS / 64, NROWS / 64);
    score_kernel<<<gB, 256, 0, stream>>>(Qb, Kb, cnt, cand);

    finalize_kernel<<<NROWS, 256, 0, stream>>>(Q, K, V, cnt, cand, out);
}

// Round 2
// 1540.524 us; speedup vs baseline: 1.4054x; 1.4054x over previous
//
#include <hip/hip_runtime.h>
#include <hip/hip_bf16.h>
#include <math.h>

#define NROWS 8192
#define DIM   1024
#define CAP   384
#define MARGIN 700.0f

using bf16x8 = __attribute__((ext_vector_type(8))) short;
using f32x4  = __attribute__((ext_vector_type(4))) float;
typedef unsigned int u32;

#define AS1 __attribute__((address_space(1)))
#define AS3 __attribute__((address_space(3)))

// ---------------- Kernel A: QKV projection, high-precision accumulate ----------
template<typename AccT, bool WB16>
__global__ __launch_bounds__(256) void qkv_gemm(const float* __restrict__ X,
                                                const float* __restrict__ W,
                                                float* __restrict__ Out,
                                                __hip_bfloat16* __restrict__ Outb) {
    __shared__ float Xs[16][68];   // transposed X tile: Xs[k][row]
    __shared__ float Ws[16][68];   // Ws[k][col]
    const int tid = threadIdx.x;
    const int tx = tid & 15, ty = tid >> 4;
    const int row0 = blockIdx.x * 64;
    const int col0 = blockIdx.y * 64;

    AccT acc[4][4];
#pragma unroll
    for (int i = 0; i < 4; ++i)
#pragma unroll
        for (int j = 0; j < 4; ++j) acc[i][j] = (AccT)0;

    const int lr = tid >> 2;          // 0..63 : X row within tile
    const int lc = (tid & 3) * 4;     // 0,4,8,12 : k within tile
    const int wr = tid >> 4;          // 0..15 : W k-row
    const int wc = (tid & 15) * 4;    // col within tile

    for (int k0 = 0; k0 < DIM; k0 += 16) {
        float4 xa = *(const float4*)&X[(size_t)(row0 + lr) * DIM + k0 + lc];
        float4 wa = *(const float4*)&W[(size_t)(k0 + wr) * DIM + col0 + wc];
        __syncthreads();
        Xs[lc + 0][lr] = xa.x;
        Xs[lc + 1][lr] = xa.y;
        Xs[lc + 2][lr] = xa.z;
        Xs[lc + 3][lr] = xa.w;
        *(float4*)&Ws[wr][wc] = wa;
        __syncthreads();
#pragma unroll
        for (int k = 0; k < 16; ++k) {
            float4 a = *(const float4*)&Xs[k][ty * 4];
            float4 b = *(const float4*)&Ws[k][tx * 4];
            float av[4] = {a.x, a.y, a.z, a.w};
            float bv[4] = {b.x, b.y, b.z, b.w};
#pragma unroll
            for (int i = 0; i < 4; ++i)
#pragma unroll
                for (int j = 0; j < 4; ++j)
                    acc[i][j] += (AccT)av[i] * (AccT)bv[j];
        }
    }
#pragma unroll
    for (int i = 0; i < 4; ++i) {
        const int row = row0 + ty * 4 + i;
#pragma unroll
        for (int j = 0; j < 4; ++j) {
            const int col = col0 + tx * 4 + j;
            float v = (float)acc[i][j];
            Out[(size_t)row * DIM + col] = v;
            if (WB16) Outb[(size_t)row * DIM + col] = __float2bfloat16(v);
        }
    }
}

// ---------------- Kernel B: m97-style 128x128 MFMA score + candidate emission --
// S = Qb @ Kb^T (both row-major [8192][1024] bf16). Block = 256 thr = 4 waves,
// wave (wy,wx) computes 64x64 via 4x4 grid of 16x16x32 MFMAs. BK=32.
// LDS staged with global_load_lds width=16 (wave-uniform base + lane*16).
__global__ __launch_bounds__(256) void score_kernel(const __hip_bfloat16* __restrict__ Qb,
                                                    const __hip_bfloat16* __restrict__ Kb,
                                                    int* __restrict__ cnt,
                                                    int2* __restrict__ cand) {
    __shared__ short As[128 * 32];   // As[row][k] row-major, 8 KB
    __shared__ short Bs[128 * 32];   // Bs[col][k] row-major, 8 KB

    const int tid  = threadIdx.x;
    const int w    = tid >> 6, lane = tid & 63;
    const int wy   = w >> 1,  wx   = w & 1;
    const int quad = lane >> 4, r16 = lane & 15;
    const int row0 = blockIdx.y * 128;
    const int col0 = blockIdx.x * 128;

    const short* q  = (const short*)Qb;
    const short* kk = (const short*)Kb;

    // staging: instruction t (t=0,1) of wave w covers tile rows [(w*2+t)*16, +16)
    // lane l -> row (w*2+t)*16 + (l>>2), 16B chunk (l&3) of the 64B row-slice.
    const int srow0 = (w * 2) * 16 + (lane >> 2);   // t=0 row
    const int schunk = (lane & 3) * 8;              // shorts
    short* ldsA0 = &As[((w * 2 + 0) * 16) * 32];
    short* ldsA1 = &As[((w * 2 + 1) * 16) * 32];
    short* ldsB0 = &Bs[((w * 2 + 0) * 16) * 32];
    short* ldsB1 = &Bs[((w * 2 + 1) * 16) * 32];

    f32x4 acc[4][4] = {};

    for (int k0 = 0; k0 < DIM; k0 += 32) {
        __syncthreads();   // prior iter's ds_reads done before overwrite
        {
            const short* ga0 = &q[(size_t)(row0 + srow0) * DIM + k0 + schunk];
            const short* ga1 = &q[(size_t)(row0 + srow0 + 16) * DIM + k0 + schunk];
            const short* gb0 = &kk[(size_t)(col0 + srow0) * DIM + k0 + schunk];
            const short* gb1 = &kk[(size_t)(col0 + srow0 + 16) * DIM + k0 + schunk];
            __builtin_amdgcn_global_load_lds((const AS1 u32*)ga0, (AS3 u32*)ldsA0, 16, 0, 0);
            __builtin_amdgcn_global_load_lds((const AS1 u32*)ga1, (AS3 u32*)ldsA1, 16, 0, 0);
            __builtin_amdgcn_global_load_lds((const AS1 u32*)gb0, (AS3 u32*)ldsB0, 16, 0, 0);
            __builtin_amdgcn_global_load_lds((const AS1 u32*)gb1, (AS3 u32*)ldsB1, 16, 0, 0);
        }
        __syncthreads();   // compiler emits vmcnt(0) drain before barrier

        bf16x8 af[4], bf[4];
#pragma unroll
        for (int m = 0; m < 4; ++m)
            af[m] = *(const bf16x8*)&As[(wy * 64 + m * 16 + r16) * 32 + quad * 8];
#pragma unroll
        for (int n = 0; n < 4; ++n)
            bf[n] = *(const bf16x8*)&Bs[(wx * 64 + n * 16 + r16) * 32 + quad * 8];
#pragma unroll
        for (int m = 0; m < 4; ++m)
#pragma unroll
            for (int n = 0; n < 4; ++n)
                acc[m][n] = __builtin_amdgcn_mfma_f32_16x16x32_bf16(af[m], bf[n], acc[m][n], 0, 0, 0);
    }

    // Epilogue: per row (m,reg): 64-col group max -> margin filter -> emit.
    // C/D layout: col = r16, row = quad*4 + reg (m89-verified).
#pragma unroll
    for (int m = 0; m < 4; ++m) {
#pragma unroll
        for (int reg = 0; reg < 4; ++reg) {
            float mx = fmaxf(fmaxf(acc[m][0][reg], acc[m][1][reg]),
                             fmaxf(acc[m][2][reg], acc[m][3][reg]));
            mx = fmaxf(mx, __shfl_xor(mx, 1, 64));
            mx = fmaxf(mx, __shfl_xor(mx, 2, 64));
            mx = fmaxf(mx, __shfl_xor(mx, 4, 64));
            mx = fmaxf(mx, __shfl_xor(mx, 8, 64));
            const float th = mx - MARGIN;
            const int row = row0 + wy * 64 + m * 16 + quad * 4 + reg;
#pragma unroll
            for (int n = 0; n < 4; ++n) {
                float s = acc[m][n][reg];
                if (s >= th) {
                    int pos = atomicAdd(&cnt[row], 1);
                    if (pos < CAP)
                        cand[(size_t)row * CAP + pos] =
                            make_int2(col0 + wx * 64 + n * 16 + r16, __float_as_int(s));
                }
            }
        }
    }
}

// ---------------- Kernel E: exact sparse softmax + V gather --------------------
__global__ __launch_bounds__(256) void finalize_kernel(const float* __restrict__ Q,
                                                       const float* __restrict__ K,
                                                       const float* __restrict__ V,
                                                       const int* __restrict__ cnt,
                                                       const int2* __restrict__ cand,
                                                       float* __restrict__ out) {
    const int i = blockIdx.x;
    const int tid = threadIdx.x;
    __shared__ float  red[256];
    __shared__ double dred[256];
    __shared__ int    surv[64];
    __shared__ double sprec[64];
    __shared__ float  wgt[64];
    __shared__ int    nsurv;

    const int c = min(cnt[i], CAP);
    float m = -3.0e38f;
    for (int t = tid; t < c; t += 256)
        m = fmaxf(m, __int_as_float(cand[(size_t)i * CAP + t].y));
    red[tid] = m;
    __syncthreads();
    for (int s = 128; s > 0; s >>= 1) {
        if (tid < s) red[tid] = fmaxf(red[tid], red[tid + s]);
        __syncthreads();
    }
    const float th = red[0] - MARGIN;
    if (tid == 0) nsurv = 0;
    __syncthreads();
    for (int t = tid; t < c; t += 256) {
        int2 e = cand[(size_t)i * CAP + t];
        if (__int_as_float(e.y) >= th) {
            int p = atomicAdd(&nsurv, 1);
            if (p < 64) surv[p] = e.x;
        }
    }
    __syncthreads();
    const int ns = min(nsurv, 64);
    for (int u = 0; u < ns; ++u) {
        const int j = surv[u];
        double a = 0.0;
        for (int d = tid; d < DIM; d += 256)
            a += (double)Q[(size_t)i * DIM + d] * (double)K[(size_t)j * DIM + d];
        dred[tid] = a;
        __syncthreads();
        for (int s = 128; s > 0; s >>= 1) {
            if (tid < s) dred[tid] += dred[tid + s];
            __syncthreads();
        }
        if (tid == 0) sprec[u] = dred[0];
        __syncthreads();
    }
    if (tid == 0) {
        double mm = -1.0e300;
        for (int u = 0; u < ns; ++u) mm = fmax(mm, sprec[u]);
        double l = 0.0;
        for (int u = 0; u < ns; ++u) l += exp(sprec[u] - mm);
        for (int u = 0; u < ns; ++u) wgt[u] = (float)(exp(sprec[u] - mm) / l);
    }
    __syncthreads();
    for (int d = tid; d < DIM; d += 256) {
        float o = 0.f;
        for (int u = 0; u < ns; ++u) o += wgt[u] * V[(size_t)surv[u] * DIM + d];
        out[(size_t)i * DIM + d] = o;
    }
}

extern "C" void kernel_launch(void* const* d_in, const int* in_sizes, int n_in,
                              void* d_out, int out_size, void* d_ws, size_t ws_size,
                              hipStream_t stream) {
    const float* X  = (const float*)d_in[0];
    const float* wq = (const float*)d_in[1];
    const float* wk = (const float*)d_in[2];
    const float* wv = (const float*)d_in[3];
    float* out = (float*)d_out;

    char* ws = (char*)d_ws;
    const size_t mat_f32 = (size_t)NROWS * DIM * 4;   // 32 MB
    const size_t mat_b16 = (size_t)NROWS * DIM * 2;   // 16 MB
    float* Q            = (float*)(ws);
    float* K            = (float*)(ws + mat_f32);
    float* V            = (float*)(ws + 2 * mat_f32);
    __hip_bfloat16* Qb  = (__hip_bfloat16*)(ws + 3 * mat_f32);
    __hip_bfloat16* Kb  = (__hip_bfloat16*)(ws + 3 * mat_f32 + mat_b16);
    int* cnt            = (int*)(ws + 3 * mat_f32 + 2 * mat_b16);
    int2* cand          = (int2*)(ws + 3 * mat_f32 + 2 * mat_b16 + (size_t)NROWS * 4);

    hipMemsetAsync(cnt, 0, (size_t)NROWS * 4, stream);

    dim3 gA(NROWS / 64, DIM / 64);
    qkv_gemm<double, true ><<<gA, 256, 0, stream>>>(X, wq, Q, Qb);
    qkv_gemm<double, true ><<<gA, 256, 0, stream>>>(X, wk, K, Kb);
    qkv_gemm<float,  false><<<gA, 256, 0, stream>>>(X, wv, V, nullptr);

    dim3 gB(NROWS / 128, NROWS / 128);
    score_kernel<<<gB, 256, 0, stream>>>(Qb, Kb, cnt, cand);

    finalize_kernel<<<NROWS, 256, 0, stream>>>(Q, K, V, cnt, cand, out);
}

// Round 3
// 1510.304 us; speedup vs baseline: 1.4335x; 1.0200x over previous
//
#include <hip/hip_runtime.h>
#include <hip/hip_bf16.h>
#include <math.h>

#define NROWS 8192
#define DIM   1024
#define CAP   384
#define MARGIN 700.0f

using bf16x8 = __attribute__((ext_vector_type(8))) short;
using f32x4  = __attribute__((ext_vector_type(4))) float;
typedef unsigned int u32;

#define AS1 __attribute__((address_space(1)))
#define AS3 __attribute__((address_space(3)))

// ---------------- Kernel A: QKV projection, high-precision accumulate ----------
template<typename AccT, bool WB16>
__global__ __launch_bounds__(256) void qkv_gemm(const float* __restrict__ X,
                                                const float* __restrict__ W,
                                                float* __restrict__ Out,
                                                __hip_bfloat16* __restrict__ Outb) {
    __shared__ float Xs[16][68];   // transposed X tile: Xs[k][row]
    __shared__ float Ws[16][68];   // Ws[k][col]
    const int tid = threadIdx.x;
    const int tx = tid & 15, ty = tid >> 4;
    const int row0 = blockIdx.x * 64;
    const int col0 = blockIdx.y * 64;

    AccT acc[4][4];
#pragma unroll
    for (int i = 0; i < 4; ++i)
#pragma unroll
        for (int j = 0; j < 4; ++j) acc[i][j] = (AccT)0;

    const int lr = tid >> 2;          // 0..63 : X row within tile
    const int lc = (tid & 3) * 4;     // 0,4,8,12 : k within tile
    const int wr = tid >> 4;          // 0..15 : W k-row
    const int wc = (tid & 15) * 4;    // col within tile

    for (int k0 = 0; k0 < DIM; k0 += 16) {
        float4 xa = *(const float4*)&X[(size_t)(row0 + lr) * DIM + k0 + lc];
        float4 wa = *(const float4*)&W[(size_t)(k0 + wr) * DIM + col0 + wc];
        __syncthreads();
        Xs[lc + 0][lr] = xa.x;
        Xs[lc + 1][lr] = xa.y;
        Xs[lc + 2][lr] = xa.z;
        Xs[lc + 3][lr] = xa.w;
        *(float4*)&Ws[wr][wc] = wa;
        __syncthreads();
#pragma unroll
        for (int k = 0; k < 16; ++k) {
            float4 a = *(const float4*)&Xs[k][ty * 4];
            float4 b = *(const float4*)&Ws[k][tx * 4];
            float av[4] = {a.x, a.y, a.z, a.w};
            float bv[4] = {b.x, b.y, b.z, b.w};
#pragma unroll
            for (int i = 0; i < 4; ++i)
#pragma unroll
                for (int j = 0; j < 4; ++j)
                    acc[i][j] += (AccT)av[i] * (AccT)bv[j];
        }
    }
#pragma unroll
    for (int i = 0; i < 4; ++i) {
        const int row = row0 + ty * 4 + i;
#pragma unroll
        for (int j = 0; j < 4; ++j) {
            const int col = col0 + tx * 4 + j;
            float v = (float)acc[i][j];
            Out[(size_t)row * DIM + col] = v;
            if (WB16) Outb[(size_t)row * DIM + col] = __float2bfloat16(v);
        }
    }
}

// ---------------- Kernel B: prefetch-dbuf 128x128 MFMA score -------------------
// S = Qb @ Kb^T. 256 thr / 4 waves, wave = 64x64 out (4x4 of 16x16x32), BK=32.
// Double-buffered LDS; loads for iter i+1 issued right after the barrier, so
// each barrier's vmcnt drain waits on loads already one full iteration old.
// One barrier per iteration. 8x8 super-tile block swizzle for L2 locality.
__global__ __launch_bounds__(256) void score_kernel(const __hip_bfloat16* __restrict__ Qb,
                                                    const __hip_bfloat16* __restrict__ Kb,
                                                    int* __restrict__ cnt,
                                                    int2* __restrict__ cand) {
    __shared__ short As[2][128 * 32];   // [buf][row][k], 16 KB
    __shared__ short Bs[2][128 * 32];   // [buf][col][k], 16 KB

    const int tid  = threadIdx.x;
    const int w    = tid >> 6, lane = tid & 63;
    const int wy   = w >> 1,  wx   = w & 1;
    const int quad = lane >> 4, r16 = lane & 15;

    // 8x8 super-tile swizzle: consecutive 64 block ids cover an 8x8 tile square
    // (Qb 2MB + Kb 2MB ~ one XCD L2); with ord%8 XCD round-robin, an XCD's 8
    // blocks of the super-tile share one Kb col tile.
    const int b      = blockIdx.x;
    const int sb     = b >> 6, within = b & 63;
    const int rowt   = ((sb >> 3) << 3) | (within >> 3);
    const int colt   = ((sb & 7) << 3) | (within & 7);
    const int row0   = rowt * 128;
    const int col0   = colt * 128;

    const short* q  = (const short*)Qb;
    const short* kk = (const short*)Kb;

    // staging map: lane l -> tile row (w*32 + (l>>2)) [+16 for 2nd inst],
    //              16B chunk (l&3) of the 64B k-slice.
    const int    srow   = w * 32 + (lane >> 2);
    const int    schunk = (lane & 3) * 8;            // shorts
    const size_t gA0 = (size_t)(row0 + srow) * DIM + schunk;
    const size_t gA1 = (size_t)(row0 + srow + 16) * DIM + schunk;
    const size_t gB0 = (size_t)(col0 + srow) * DIM + schunk;
    const size_t gB1 = (size_t)(col0 + srow + 16) * DIM + schunk;
    short* ldsA0_base[2] = { &As[0][(w * 32) * 32],      &As[1][(w * 32) * 32] };
    short* ldsA1_base[2] = { &As[0][(w * 32 + 16) * 32], &As[1][(w * 32 + 16) * 32] };
    short* ldsB0_base[2] = { &Bs[0][(w * 32) * 32],      &Bs[1][(w * 32) * 32] };
    short* ldsB1_base[2] = { &Bs[0][(w * 32 + 16) * 32], &Bs[1][(w * 32 + 16) * 32] };

    f32x4 acc[4][4] = {};

    // preload iter 0 into buf 0
    {
        __builtin_amdgcn_global_load_lds((const AS1 u32*)(q  + gA0), (AS3 u32*)ldsA0_base[0], 16, 0, 0);
        __builtin_amdgcn_global_load_lds((const AS1 u32*)(q  + gA1), (AS3 u32*)ldsA1_base[0], 16, 0, 0);
        __builtin_amdgcn_global_load_lds((const AS1 u32*)(kk + gB0), (AS3 u32*)ldsB0_base[0], 16, 0, 0);
        __builtin_amdgcn_global_load_lds((const AS1 u32*)(kk + gB1), (AS3 u32*)ldsB1_base[0], 16, 0, 0);
    }

    for (int i = 0; i < 32; ++i) {
        const int p = i & 1;
        __syncthreads();   // drains vmcnt: loads(i) complete; all iter i-1 ds_reads done
        if (i + 1 < 32) {
            const size_t k1 = (size_t)(i + 1) * 32;
            __builtin_amdgcn_global_load_lds((const AS1 u32*)(q  + gA0 + k1), (AS3 u32*)ldsA0_base[1 - p], 16, 0, 0);
            __builtin_amdgcn_global_load_lds((const AS1 u32*)(q  + gA1 + k1), (AS3 u32*)ldsA1_base[1 - p], 16, 0, 0);
            __builtin_amdgcn_global_load_lds((const AS1 u32*)(kk + gB0 + k1), (AS3 u32*)ldsB0_base[1 - p], 16, 0, 0);
            __builtin_amdgcn_global_load_lds((const AS1 u32*)(kk + gB1 + k1), (AS3 u32*)ldsB1_base[1 - p], 16, 0, 0);
        }

        bf16x8 af[4], bfr[4];
#pragma unroll
        for (int m = 0; m < 4; ++m)
            af[m] = *(const bf16x8*)&As[p][(wy * 64 + m * 16 + r16) * 32 + quad * 8];
#pragma unroll
        for (int n = 0; n < 4; ++n)
            bfr[n] = *(const bf16x8*)&Bs[p][(wx * 64 + n * 16 + r16) * 32 + quad * 8];
#pragma unroll
        for (int m = 0; m < 4; ++m)
#pragma unroll
            for (int n = 0; n < 4; ++n)
                acc[m][n] = __builtin_amdgcn_mfma_f32_16x16x32_bf16(af[m], bfr[n], acc[m][n], 0, 0, 0);
    }

    // Epilogue: per row: 64-col group max -> margin filter -> emit.
    // C/D layout: col = r16, row = quad*4 + reg (m89-verified, R2-passed).
#pragma unroll
    for (int m = 0; m < 4; ++m) {
#pragma unroll
        for (int reg = 0; reg < 4; ++reg) {
            float mx = fmaxf(fmaxf(acc[m][0][reg], acc[m][1][reg]),
                             fmaxf(acc[m][2][reg], acc[m][3][reg]));
            mx = fmaxf(mx, __shfl_xor(mx, 1, 64));
            mx = fmaxf(mx, __shfl_xor(mx, 2, 64));
            mx = fmaxf(mx, __shfl_xor(mx, 4, 64));
            mx = fmaxf(mx, __shfl_xor(mx, 8, 64));
            const float th = mx - MARGIN;
            const int row = row0 + wy * 64 + m * 16 + quad * 4 + reg;
#pragma unroll
            for (int n = 0; n < 4; ++n) {
                float s = acc[m][n][reg];
                if (s >= th) {
                    int pos = atomicAdd(&cnt[row], 1);
                    if (pos < CAP)
                        cand[(size_t)row * CAP + pos] =
                            make_int2(col0 + wx * 64 + n * 16 + r16, __float_as_int(s));
                }
            }
        }
    }
}

// ---------------- Kernel E: exact sparse softmax + V gather --------------------
__global__ __launch_bounds__(256) void finalize_kernel(const float* __restrict__ Q,
                                                       const float* __restrict__ K,
                                                       const float* __restrict__ V,
                                                       const int* __restrict__ cnt,
                                                       const int2* __restrict__ cand,
                                                       float* __restrict__ out) {
    const int i = blockIdx.x;
    const int tid = threadIdx.x;
    const int w = tid >> 6, lane = tid & 63;
    __shared__ float  red[256];
    __shared__ int    surv[64];
    __shared__ double sprec[64];
    __shared__ float  wgt[64];
    __shared__ int    nsurv;

    const int c = min(cnt[i], CAP);
    // phase 1: global max of approximate scores
    float m = -3.0e38f;
    for (int t = tid; t < c; t += 256)
        m = fmaxf(m, __int_as_float(cand[(size_t)i * CAP + t].y));
    red[tid] = m;
    __syncthreads();
    for (int s = 128; s > 0; s >>= 1) {
        if (tid < s) red[tid] = fmaxf(red[tid], red[tid + s]);
        __syncthreads();
    }
    const float th = red[0] - MARGIN;
    if (tid == 0) nsurv = 0;
    __syncthreads();
    // phase 2: survivors
    for (int t = tid; t < c; t += 256) {
        int2 e = cand[(size_t)i * CAP + t];
        if (__int_as_float(e.y) >= th) {
            int p = atomicAdd(&nsurv, 1);
            if (p < 64) surv[p] = e.x;
        }
    }
    __syncthreads();
    const int ns = min(nsurv, 64);
    // phase 3: fp64 precise rescore, one survivor per wave (wave-parallel)
    for (int u = w; u < ns; u += 4) {
        const int j = surv[u];
        double a = 0.0;
        for (int d = lane; d < DIM; d += 64)
            a += (double)Q[(size_t)i * DIM + d] * (double)K[(size_t)j * DIM + d];
#pragma unroll
        for (int o = 32; o > 0; o >>= 1)
            a += __shfl_down(a, o, 64);
        if (lane == 0) sprec[u] = a;
    }
    __syncthreads();
    // phase 4: exact softmax over survivors
    if (tid == 0) {
        double mm = -1.0e300;
        for (int u = 0; u < ns; ++u) mm = fmax(mm, sprec[u]);
        double l = 0.0;
        for (int u = 0; u < ns; ++u) l += exp(sprec[u] - mm);
        for (int u = 0; u < ns; ++u) wgt[u] = (float)(exp(sprec[u] - mm) / l);
    }
    __syncthreads();
    // phase 5: weighted gather of V rows
    for (int d = tid; d < DIM; d += 256) {
        float o = 0.f;
        for (int u = 0; u < ns; ++u) o += wgt[u] * V[(size_t)surv[u] * DIM + d];
        out[(size_t)i * DIM + d] = o;
    }
}

extern "C" void kernel_launch(void* const* d_in, const int* in_sizes, int n_in,
                              void* d_out, int out_size, void* d_ws, size_t ws_size,
                              hipStream_t stream) {
    const float* X  = (const float*)d_in[0];
    const float* wq = (const float*)d_in[1];
    const float* wk = (const float*)d_in[2];
    const float* wv = (const float*)d_in[3];
    float* out = (float*)d_out;

    char* ws = (char*)d_ws;
    const size_t mat_f32 = (size_t)NROWS * DIM * 4;   // 32 MB
    const size_t mat_b16 = (size_t)NROWS * DIM * 2;   // 16 MB
    float* Q            = (float*)(ws);
    float* K            = (float*)(ws + mat_f32);
    float* V            = (float*)(ws + 2 * mat_f32);
    __hip_bfloat16* Qb  = (__hip_bfloat16*)(ws + 3 * mat_f32);
    __hip_bfloat16* Kb  = (__hip_bfloat16*)(ws + 3 * mat_f32 + mat_b16);
    int* cnt            = (int*)(ws + 3 * mat_f32 + 2 * mat_b16);
    int2* cand          = (int2*)(ws + 3 * mat_f32 + 2 * mat_b16 + (size_t)NROWS * 4);

    hipMemsetAsync(cnt, 0, (size_t)NROWS * 4, stream);

    dim3 gA(NROWS / 64, DIM / 64);
    qkv_gemm<double, true ><<<gA, 256, 0, stream>>>(X, wq, Q, Qb);
    qkv_gemm<double, true ><<<gA, 256, 0, stream>>>(X, wk, K, Kb);
    qkv_gemm<float,  false><<<gA, 256, 0, stream>>>(X, wv, V, nullptr);

    score_kernel<<<4096, 256, 0, stream>>>(Qb, Kb, cnt, cand);

    finalize_kernel<<<NROWS, 256, 0, stream>>>(Q, K, V, cnt, cand, out);
}